// Round 1
// baseline (911.177 us; speedup 1.0000x reference)
//
#include <hip/hip_runtime.h>
#include <hip/hip_bf16.h>
#include <stdint.h>

#define DIM   1024
#define NE    8
#define HID   2730
#define HPAD  2816      // 44*64; w2b zero-padded so h's pad cols contribute 0
#define NTOK  8192      // B*N = 4*2048
#define CAP   8192      // max tokens per expert
#define NSLOT 16384     // NTOK * TOP_K
#define MAXB  72        // sum_e ceil(M_e/256) <= 16384/256 + 8 = 72
#define NCH1  32        // gemm1 K chunks of 32 (K=1024)
#define NCH2  44        // gemm2 K chunks of 32 per split-K half (1408)

typedef __bf16 bf16x8 __attribute__((ext_vector_type(8)));
typedef float  floatx4 __attribute__((ext_vector_type(4)));

__device__ __forceinline__ unsigned short f2bf(float f) {
    union { float f; unsigned int u; } v; v.f = f;
    unsigned int u = v.u;
    unsigned int r = (u + 0x7fffu + ((u >> 16) & 1u)) >> 16;  // RNE
    return (unsigned short)r;
}

__device__ __forceinline__ float bf2f(unsigned short b) {
    union { unsigned int u; float f; } v; v.u = (unsigned int)b << 16;
    return v.f;
}

__device__ __forceinline__ void gl2lds16(const void* g, void* l) {
    __builtin_amdgcn_global_load_lds((const __attribute__((address_space(1))) void*)g,
                                     (__attribute__((address_space(3))) void*)l,
                                     16, 0, 0);
}

// ---------------- merged weight conversion (w1, w3, w2) + scalar init ----------------
__global__ void convert_w_kernel(const float* __restrict__ w1, const float* __restrict__ w3,
                                 const float* __restrict__ w2,
                                 unsigned short* __restrict__ w1b, unsigned short* __restrict__ w3b,
                                 unsigned short* __restrict__ w2b,
                                 int* __restrict__ counts, float* __restrict__ psum) {
    const int HALF = (NE * HID * DIM) / 4;   // 5,591,040 float4 chunks per w1/w3
    const int W13  = 2 * HALF;               // 11,182,080
    int gid = blockIdx.x * 256 + threadIdx.x;
    if (blockIdx.x == 0 && threadIdx.x < 64) {   // ordered before router (separate dispatch)
        counts[threadIdx.x & 15] = 0;
        psum[threadIdx.x & 15] = 0.f;
    }
    if (gid < W13) {
        const float* src; unsigned short* dst; int j;
        if (gid < HALF) { src = w1; dst = w1b; j = gid; }
        else            { src = w3; dst = w3b; j = gid - HALF; }
        float4 v = ((const float4*)src)[j];
        uint2 o;
        o.x = (unsigned)f2bf(v.x) | ((unsigned)f2bf(v.y) << 16);
        o.y = (unsigned)f2bf(v.z) | ((unsigned)f2bf(v.w) << 16);
        *(uint2*)(dst + (size_t)j * 4) = o;
    } else {
        int i = gid - W13;                   // 8192 rows * 704 chunks
        int r = i / 704;
        int c = (i - r * 704) * 4;
        const float* src = w2 + (size_t)r * HID;
        unsigned short q[4];
        if (c + 3 < HID) {                   // rows are 8B-aligned (2730*4 % 8 == 0)
            float2 v0 = *(const float2*)(src + c);
            float2 v1 = *(const float2*)(src + c + 2);
            q[0] = f2bf(v0.x); q[1] = f2bf(v0.y); q[2] = f2bf(v1.x); q[3] = f2bf(v1.y);
        } else {
#pragma unroll
            for (int j = 0; j < 4; ++j) {
                int col = c + j;
                q[j] = (col < HID) ? f2bf(src[col]) : (unsigned short)0;  // zero pad
            }
        }
        uint2 o;
        o.x = (unsigned)q[0] | ((unsigned)q[1] << 16);
        o.y = (unsigned)q[2] | ((unsigned)q[3] << 16);
        *(uint2*)(w2b + (size_t)r * HPAD + c) = o;
    }
}

// ---------------- router (also emits xb = bf16(x)) ----------------
__global__ void router_kernel(const float* __restrict__ x, const float* __restrict__ gw,
                              unsigned short* __restrict__ xb,
                              int* __restrict__ toks, int* __restrict__ meta,
                              float* __restrict__ tokw,
                              int* __restrict__ counts, float* __restrict__ psum) {
    __shared__ float gws[NE * DIM];        // 32 KB
    __shared__ float pblk[4][NE];
    int t = threadIdx.x;
    for (int i = t; i < NE * DIM; i += 256) gws[i] = gw[i];
    __syncthreads();

    int wv = t >> 6, lane = t & 63;
    int tok = blockIdx.x * 4 + wv;
    const float4* x4 = (const float4*)(x + (size_t)tok * DIM);
    uint2* xbrow = (uint2*)(xb + (size_t)tok * DIM);

    float p[NE];
#pragma unroll
    for (int e = 0; e < NE; ++e) p[e] = 0.f;
#pragma unroll
    for (int c = 0; c < 4; ++c) {
        float4 xv = x4[c * 64 + lane];
        uint2 o;
        o.x = (unsigned)f2bf(xv.x) | ((unsigned)f2bf(xv.y) << 16);
        o.y = (unsigned)f2bf(xv.z) | ((unsigned)f2bf(xv.w) << 16);
        xbrow[c * 64 + lane] = o;
#pragma unroll
        for (int e = 0; e < NE; ++e) {
            float4 gv = ((const float4*)(gws + e * DIM))[c * 64 + lane];
            p[e] += xv.x * gv.x + xv.y * gv.y + xv.z * gv.z + xv.w * gv.w;
        }
    }
#pragma unroll
    for (int e = 0; e < NE; ++e)
#pragma unroll
        for (int s = 32; s; s >>= 1) p[e] += __shfl_xor(p[e], s, 64);

    if (lane == 0) {
        float mx = p[0];
#pragma unroll
        for (int e = 1; e < NE; ++e) mx = fmaxf(mx, p[e]);
        float ex[NE], s = 0.f;
#pragma unroll
        for (int e = 0; e < NE; ++e) { ex[e] = __expf(p[e] - mx); s += ex[e]; }
        float inv = 1.f / s;
        int i1 = 0, i2 = 0; float v1 = -1.f, v2 = -1.f;
#pragma unroll
        for (int e = 0; e < NE; ++e) {
            float pe = ex[e] * inv;
            pblk[wv][e] = pe;
            if (pe > v1)      { v2 = v1; i2 = i1; v1 = pe; i1 = e; }
            else if (pe > v2) { v2 = pe; i2 = e; }
        }
        float wn = 1.f / (v1 + v2);
        int p1 = atomicAdd(&counts[i1], 1);
        toks[i1 * CAP + p1] = tok;
        meta[tok * 2]     = (i1 << 16) | p1;
        tokw[tok * 2]     = v1 * wn;
        int p2 = atomicAdd(&counts[i2], 1);
        toks[i2 * CAP + p2] = tok;
        meta[tok * 2 + 1] = (i2 << 16) | p2;
        tokw[tok * 2 + 1] = v2 * wn;
    }
    __syncthreads();
    if (t < NE) {
        float s = pblk[0][t] + pblk[1][t] + pblk[2][t] + pblk[3][t];
        atomicAdd(&psum[t], s);
    }
}

// finalize: prefix offsets, aux loss, and the live 256-row block table.
// Live slots are dealt into 8 XCD groups of 9 positions so padding (dead slots)
// is spread evenly across XCDs (blocked swizzle would starve the last XCD).
__global__ void finalize_kernel(const int* __restrict__ counts, int* __restrict__ offs,
                                const float* __restrict__ psum, float* __restrict__ aux_out,
                                int* __restrict__ blk_e, int* __restrict__ blk_m0) {
    if (threadIdx.x == 0) {
        int le[MAXB], lm[MAXB];
        int off = 0, nb = 0;
        for (int e = 0; e < NE; ++e) {
            offs[e] = off;
            int M = counts[e];
            off += M;
            for (int m0 = 0; m0 < M; m0 += 256) { le[nb] = e; lm[nb] = m0; ++nb; }
        }
        int base = 0;
        for (int q = 0; q < 8; ++q) {
            int n_q = nb / 8 + ((q < (nb & 7)) ? 1 : 0);
            for (int s = 0; s < 9; ++s) {
                int p = q * 9 + s;
                if (s < n_q) { blk_e[p] = le[base + s]; blk_m0[p] = lm[base + s]; }
                else         { blk_e[p] = 0; blk_m0[p] = 0x7fffffff; }
            }
            base += n_q;
        }
        float sfl = 0.f;
        for (int e = 0; e < NE; ++e) {
            float d = psum[e] * (1.f / NTOK) - (1.f / NE);
            sfl += d * d;
        }
        aux_out[0] = 0.01f * sfl * (1.f / NE);
    }
}

// ---------------- stage-1: h = silu(x@w1^T) * (x@w3^T) ----------------
// 256(M)x128(N) tile, dual-B, 8 waves. 4-slot LDS ring over 32-col K-chunks,
// prefetch distance 3 chunks, counted vmcnt(8) at chunk boundaries (never 0
// mid-loop), raw s_barrier + lgkmcnt(0) + setprio around 16-MFMA clusters.
// LDS swizzle: phys 16B chunk = lq ^ ((lr>>1)&3), applied by pre-swizzling the
// per-lane GLOBAL source (gl2lds dest must be linear) -> 2-way/quarter-wave = free.
__global__ __launch_bounds__(512, 2) void gemm1_kernel(
    const unsigned short* __restrict__ xb,
    const unsigned short* __restrict__ w1b,
    const unsigned short* __restrict__ w3b,
    unsigned short* __restrict__ h,
    const int* __restrict__ counts, const int* __restrict__ offs,
    const int* __restrict__ toks,
    const int* __restrict__ blk_e, const int* __restrict__ blk_m0) {
    const int id = blockIdx.x;
    const int q  = id & 7;                 // XCD class
    const int k  = id >> 3;                // < 198
    const int xp = k % 22;
    const int slot = q * 9 + k / 22;       // all 22 n-blocks of a slot share XCD
    const int e  = blk_e[slot];
    const int m0 = blk_m0[slot];
    const int M  = counts[e];
    if (m0 >= M) return;
    const int n0 = xp * 128;
    const int hb = offs[e];

    __shared__ unsigned short As[4][256 * 32];   // 64 KB
    __shared__ unsigned short B1s[4][128 * 32];  // 32 KB
    __shared__ unsigned short B3s[4][128 * 32];  // 32 KB

    const int t = threadIdx.x;
    const int wv = t >> 6, l = t & 63;
    // staging geometry: wave wv stages rows wv*16..wv*16+15 (lane covers 16B)
    const int srow  = wv * 16 + (l >> 2);             // 0..127
    const int cl    = (l & 3) ^ ((l >> 3) & 3);       // pre-swizzled source chunk
    const int stoff = wv * 512 + l * 8;               // ushort offset in slot
    const int* tl = toks + e * CAP;
    const int ar0 = tl[min(m0 + srow, M - 1)];
    const int ar1 = tl[min(m0 + 128 + srow, M - 1)];
    const int br  = min(n0 + srow, HID - 1);
    const unsigned short* ap0 = xb + (size_t)ar0 * DIM + cl * 8;
    const unsigned short* ap1 = xb + (size_t)ar1 * DIM + cl * 8;
    const unsigned short* bp1 = w1b + ((size_t)e * HID + br) * DIM + cl * 8;
    const unsigned short* bp3 = w3b + ((size_t)e * HID + br) * DIM + cl * 8;

    // MFMA fragment geometry: per-wave 128(M)x32(N), 8 m-frags x 2 n-frags x 2 mats
    const int lq = l >> 4, lr = l & 15;
    const int wm = (wv & 1) * 128, wn = (wv >> 1) * 32;
    const int pc8 = (lq ^ ((lr >> 1) & 3)) * 8;       // swizzled read chunk
    int aoff[8], boff[2];
#pragma unroll
    for (int mi = 0; mi < 8; ++mi) aoff[mi] = (wm + mi * 16 + lr) * 32 + pc8;
#pragma unroll
    for (int ni = 0; ni < 2; ++ni) boff[ni] = (wn + ni * 16 + lr) * 32 + pc8;

    floatx4 acc1[8][2], acc3[8][2];
#pragma unroll
    for (int a = 0; a < 8; ++a)
#pragma unroll
        for (int b = 0; b < 2; ++b) {
            acc1[a][b] = (floatx4){0.f, 0.f, 0.f, 0.f};
            acc3[a][b] = (floatx4){0.f, 0.f, 0.f, 0.f};
        }

    // prologue: stage chunks 0..2 (4 loads each, grouped per chunk for FIFO vmcnt)
#pragma unroll
    for (int pc = 0; pc < 3; ++pc) {
        gl2lds16(ap0 + pc * 32, &As[pc][stoff]);
        gl2lds16(ap1 + pc * 32, &As[pc][4096 + stoff]);
        gl2lds16(bp1 + pc * 32, &B1s[pc][stoff]);
        gl2lds16(bp3 + pc * 32, &B3s[pc][stoff]);
    }

    for (int c = 0; c < NCH1; ++c) {
        const int sl = c & 3;
        // boundary: chunk c's 4 loads (issued 3 chunks ago) are the oldest beyond N
        if (c + 2 < NCH1)      asm volatile("s_waitcnt vmcnt(8)" ::: "memory");
        else if (c + 1 < NCH1) asm volatile("s_waitcnt vmcnt(4)" ::: "memory");
        else                   asm volatile("s_waitcnt vmcnt(0)" ::: "memory");
        __builtin_amdgcn_s_barrier();
        const unsigned short* Az  = As[sl];
        const unsigned short* B1z = B1s[sl];
        const unsigned short* B3z = B3s[sl];
        bf16x8 af[4], bf1[2], bf3[2];
        // even phase: B frags + A m-frags 0-3, stage A of chunk c+3
#pragma unroll
        for (int ni = 0; ni < 2; ++ni) {
            bf1[ni] = *(const bf16x8*)(B1z + boff[ni]);
            bf3[ni] = *(const bf16x8*)(B3z + boff[ni]);
        }
#pragma unroll
        for (int mi = 0; mi < 4; ++mi) af[mi] = *(const bf16x8*)(Az + aoff[mi]);
        if (c + 3 < NCH1) {
            const int cs = c + 3, s2 = cs & 3;
            gl2lds16(ap0 + cs * 32, &As[s2][stoff]);
            gl2lds16(ap1 + cs * 32, &As[s2][4096 + stoff]);
        }
        __builtin_amdgcn_s_barrier();
        asm volatile("s_waitcnt lgkmcnt(0)" ::: "memory");
        __builtin_amdgcn_s_setprio(1);
#pragma unroll
        for (int mi = 0; mi < 4; ++mi)
#pragma unroll
            for (int ni = 0; ni < 2; ++ni) {
                acc1[mi][ni] = __builtin_amdgcn_mfma_f32_16x16x32_bf16(af[mi], bf1[ni], acc1[mi][ni], 0, 0, 0);
                acc3[mi][ni] = __builtin_amdgcn_mfma_f32_16x16x32_bf16(af[mi], bf3[ni], acc3[mi][ni], 0, 0, 0);
            }
        __builtin_amdgcn_s_setprio(0);
        __builtin_amdgcn_s_barrier();
        // odd phase: A m-frags 4-7 (B frags reused), stage B1/B3 of chunk c+3
#pragma unroll
        for (int mi = 0; mi < 4; ++mi) af[mi] = *(const bf16x8*)(Az + aoff[mi + 4]);
        if (c + 3 < NCH1) {
            const int cs = c + 3, s2 = cs & 3;
            gl2lds16(bp1 + cs * 32, &B1s[s2][stoff]);
            gl2lds16(bp3 + cs * 32, &B3s[s2][stoff]);
        }
        __builtin_amdgcn_s_barrier();
        asm volatile("s_waitcnt lgkmcnt(0)" ::: "memory");
        __builtin_amdgcn_s_setprio(1);
#pragma unroll
        for (int mi = 0; mi < 4; ++mi)
#pragma unroll
            for (int ni = 0; ni < 2; ++ni) {
                acc1[mi + 4][ni] = __builtin_amdgcn_mfma_f32_16x16x32_bf16(af[mi], bf1[ni], acc1[mi + 4][ni], 0, 0, 0);
                acc3[mi + 4][ni] = __builtin_amdgcn_mfma_f32_16x16x32_bf16(af[mi], bf3[ni], acc3[mi + 4][ni], 0, 0, 0);
            }
        __builtin_amdgcn_s_setprio(0);
        // trailing barrier == next iteration's top barrier
    }

#pragma unroll
    for (int mi = 0; mi < 8; ++mi)
#pragma unroll
        for (int rg = 0; rg < 4; ++rg) {
            const int gm = m0 + wm + mi * 16 + lq * 4 + rg;
            if (gm >= M) continue;
            unsigned short* hrow = h + (size_t)(hb + gm) * HPAD;
#pragma unroll
            for (int ni = 0; ni < 2; ++ni) {
                const int col = n0 + wn + ni * 16 + lr;   // < 2816 always
                float z1 = acc1[mi][ni][rg];
                float z3 = acc3[mi][ni][rg];
                hrow[col] = f2bf(z1 / (1.f + __expf(-z1)) * z3);   // silu(z1)*z3
            }
        }
}

// ---------------- stage-2: split-K=2 bf16 partials y[kh][slot] = h @ w2^T ----------------
// 256(M)x128(N) tile, single B, same ring/counted-vmcnt structure (3 loads/chunk).
// Per-wave 64x64 (4M x 2N wave grid), 16 MFMA per chunk-phase.
__global__ __launch_bounds__(512, 2) void gemm2_kernel(
    const unsigned short* __restrict__ h,
    const unsigned short* __restrict__ w2b,
    unsigned short* __restrict__ yh,            // [2][NSLOT][DIM] bf16 partials
    const int* __restrict__ counts, const int* __restrict__ offs,
    const int* __restrict__ blk_e, const int* __restrict__ blk_m0) {
    const int id = blockIdx.x;
    const int q  = id & 7;
    const int k  = id >> 3;                // < 144
    const int xp = k & 7;
    const int g  = k >> 3;                 // < 18
    const int combo = q * 18 + g;          // < 144; same (slot,kh) n-blocks share XCD
    const int slot = combo % MAXB;
    const int kh   = combo / MAXB;
    const int e  = blk_e[slot];
    const int m0 = blk_m0[slot];
    const int M  = counts[e];
    if (m0 >= M) return;
    const int n0 = xp * 128;
    const int hb = offs[e];

    __shared__ unsigned short As[4][256 * 32];   // 64 KB
    __shared__ unsigned short Bs[4][128 * 32];   // 32 KB

    const int t = threadIdx.x;
    const int wv = t >> 6, l = t & 63;
    const int srow  = wv * 16 + (l >> 2);
    const int cl    = (l & 3) ^ ((l >> 3) & 3);
    const int stoff = wv * 512 + l * 8;
    const int ar0 = hb + min(m0 + srow, M - 1);
    const int ar1 = hb + min(m0 + 128 + srow, M - 1);
    const int kb  = kh * (NCH2 * 32);            // split-K element base
    const unsigned short* ap0 = h + (size_t)ar0 * HPAD + kb + cl * 8;
    const unsigned short* ap1 = h + (size_t)ar1 * HPAD + kb + cl * 8;
    const unsigned short* bp  = w2b + ((size_t)e * DIM + n0 + srow) * HPAD + kb + cl * 8;

    const int lq = l >> 4, lr = l & 15;
    const int wm = (wv >> 1) * 64, wn = (wv & 1) * 64;
    const int pc8 = (lq ^ ((lr >> 1) & 3)) * 8;
    int aoff[4], boff[4];
#pragma unroll
    for (int mi = 0; mi < 4; ++mi) aoff[mi] = (wm + mi * 16 + lr) * 32 + pc8;
#pragma unroll
    for (int ni = 0; ni < 4; ++ni) boff[ni] = (wn + ni * 16 + lr) * 32 + pc8;

    floatx4 acc[4][4];
#pragma unroll
    for (int a = 0; a < 4; ++a)
#pragma unroll
        for (int b = 0; b < 4; ++b) acc[a][b] = (floatx4){0.f, 0.f, 0.f, 0.f};

#pragma unroll
    for (int pc = 0; pc < 3; ++pc) {
        gl2lds16(ap0 + pc * 32, &As[pc][stoff]);
        gl2lds16(ap1 + pc * 32, &As[pc][4096 + stoff]);
        gl2lds16(bp  + pc * 32, &Bs[pc][stoff]);
    }

    for (int c = 0; c < NCH2; ++c) {
        const int sl = c & 3;
        if (c + 2 < NCH2)      asm volatile("s_waitcnt vmcnt(6)" ::: "memory");
        else if (c + 1 < NCH2) asm volatile("s_waitcnt vmcnt(3)" ::: "memory");
        else                   asm volatile("s_waitcnt vmcnt(0)" ::: "memory");
        __builtin_amdgcn_s_barrier();
        const unsigned short* Az = As[sl];
        const unsigned short* Bz = Bs[sl];
        bf16x8 af[4], bf[4];
#pragma unroll
        for (int ni = 0; ni < 4; ++ni) bf[ni] = *(const bf16x8*)(Bz + boff[ni]);
#pragma unroll
        for (int mi = 0; mi < 4; ++mi) af[mi] = *(const bf16x8*)(Az + aoff[mi]);
        if (c + 3 < NCH2) {
            const int cs = c + 3, s2 = cs & 3;
            gl2lds16(ap0 + cs * 32, &As[s2][stoff]);
            gl2lds16(ap1 + cs * 32, &As[s2][4096 + stoff]);
            gl2lds16(bp  + cs * 32, &Bs[s2][stoff]);
        }
        __builtin_amdgcn_s_barrier();
        asm volatile("s_waitcnt lgkmcnt(0)" ::: "memory");
        __builtin_amdgcn_s_setprio(1);
#pragma unroll
        for (int mi = 0; mi < 4; ++mi)
#pragma unroll
            for (int ni = 0; ni < 4; ++ni)
                acc[mi][ni] = __builtin_amdgcn_mfma_f32_16x16x32_bf16(af[mi], bf[ni], acc[mi][ni], 0, 0, 0);
        __builtin_amdgcn_s_setprio(0);
    }

    unsigned short* ybase = yh + (size_t)kh * NSLOT * DIM;
#pragma unroll
    for (int mi = 0; mi < 4; ++mi)
#pragma unroll
        for (int rg = 0; rg < 4; ++rg) {
            const int gm = m0 + wm + mi * 16 + lq * 4 + rg;
            if (gm >= M) continue;
            unsigned short* yrow = ybase + (size_t)(hb + gm) * DIM;
#pragma unroll
            for (int ni = 0; ni < 4; ++ni)
                yrow[n0 + wn + ni * 16 + lr] = f2bf(acc[mi][ni][rg]);
        }
}

// ---------------- combine: out[tok] = w0*(y0[s0]+y1[s0]) + w1*(y0[s1]+y1[s1]) ----------------
__global__ void combine_kernel(const unsigned short* __restrict__ yh,
                               const int* __restrict__ meta,
                               const float* __restrict__ tokw,
                               const int* __restrict__ offs,
                               float* __restrict__ out) {
    const int tok = blockIdx.x;
    const int t = threadIdx.x;                      // 256 threads x 4 floats = 1024
    const int m0 = meta[tok * 2], m1 = meta[tok * 2 + 1];
    const float w0 = tokw[tok * 2], w1 = tokw[tok * 2 + 1];
    const size_t r0 = (size_t)(offs[m0 >> 16] + (m0 & 0xffff)) * DIM;
    const size_t r1 = (size_t)(offs[m1 >> 16] + (m1 & 0xffff)) * DIM;
    const unsigned short* p0 = yh;
    const unsigned short* p1 = yh + (size_t)NSLOT * DIM;
    uint2 a0 = ((const uint2*)(p0 + r0))[t];
    uint2 a1 = ((const uint2*)(p1 + r0))[t];
    uint2 b0 = ((const uint2*)(p0 + r1))[t];
    uint2 b1 = ((const uint2*)(p1 + r1))[t];
    float4 o;
    o.x = w0 * (bf2f(a0.x & 0xffff) + bf2f(a1.x & 0xffff)) + w1 * (bf2f(b0.x & 0xffff) + bf2f(b1.x & 0xffff));
    o.y = w0 * (bf2f(a0.x >> 16)    + bf2f(a1.x >> 16))    + w1 * (bf2f(b0.x >> 16)    + bf2f(b1.x >> 16));
    o.z = w0 * (bf2f(a0.y & 0xffff) + bf2f(a1.y & 0xffff)) + w1 * (bf2f(b0.y & 0xffff) + bf2f(b1.y & 0xffff));
    o.w = w0 * (bf2f(a0.y >> 16)    + bf2f(a1.y >> 16))    + w1 * (bf2f(b0.y >> 16)    + bf2f(b1.y >> 16));
    ((float4*)(out + (size_t)tok * DIM))[t] = o;
}

extern "C" void kernel_launch(void* const* d_in, const int* in_sizes, int n_in,
                              void* d_out, int out_size, void* d_ws, size_t ws_size,
                              hipStream_t stream) {
    const float* x  = (const float*)d_in[0];
    const float* gw = (const float*)d_in[1];
    const float* w1 = (const float*)d_in[2];
    const float* w2 = (const float*)d_in[3];   // dict order: w1, w2, w3
    const float* w3 = (const float*)d_in[4];
    float* out = (float*)d_out;

    char* ws = (char*)d_ws;
    size_t o = 0;
    auto alloc = [&](size_t bytes) -> void* {
        void* p = ws + o;
        o += (bytes + 255) & ~(size_t)255;
        return p;
    };
    unsigned short* xb   = (unsigned short*)alloc((size_t)NTOK * DIM * 2);       // 16.8 MB
    unsigned short* w1b  = (unsigned short*)alloc((size_t)NE * HID * DIM * 2);   // 44.7 MB
    unsigned short* w3b  = (unsigned short*)alloc((size_t)NE * HID * DIM * 2);   // 44.7 MB
    unsigned short* w2b  = (unsigned short*)alloc((size_t)NE * DIM * HPAD * 2);  // 46.1 MB
    unsigned short* hbuf = (unsigned short*)alloc((size_t)NSLOT * HPAD * 2);     // 92.3 MB
    int*   toks   = (int*)alloc((size_t)NE * CAP * 4);
    int*   meta   = (int*)alloc((size_t)NTOK * 2 * 4);
    float* tokw   = (float*)alloc((size_t)NTOK * 2 * 4);
    int*   counts = (int*)alloc(256);
    float* psum   = (float*)alloc(256);
    int*   offs   = (int*)alloc(256);
    int*   blk_e  = (int*)alloc(MAXB * 4);
    int*   blk_m0 = (int*)alloc(MAXB * 4);
    if (o > ws_size) return;
    // bf16 split-K partials: 2 x 16384 x 1024 x 2 B = 67.1 MB, aliased over
    // xb+w1b+w3b (106 MB) -- all three are dead once gemm1 completes, and
    // gemm2 (which writes yh) is stream-ordered after gemm1.
    unsigned short* yh = (unsigned short*)xb;

    convert_w_kernel<<<66208, 256, 0, stream>>>(w1, w3, w2, w1b, w3b, w2b, counts, psum);
    router_kernel<<<2048, 256, 0, stream>>>(x, gw, xb, toks, meta, tokw, counts, psum);
    finalize_kernel<<<1, 64, 0, stream>>>(counts, offs, psum, out + (size_t)NTOK * DIM, blk_e, blk_m0);
    gemm1_kernel<<<1584, 512, 0, stream>>>(xb, w1b, w3b, hbuf, counts, offs, toks, blk_e, blk_m0);
    gemm2_kernel<<<1152, 512, 0, stream>>>(hbuf, w2b, yh, counts, offs, blk_e, blk_m0);
    combine_kernel<<<NTOK, 256, 0, stream>>>(yh, meta, tokw, offs, out);
}

// Round 2
// 835.437 us; speedup vs baseline: 1.0907x; 1.0907x over previous
//
#include <hip/hip_runtime.h>
#include <hip/hip_bf16.h>
#include <stdint.h>

#define DIM   1024
#define NE    8
#define HID   2730
#define HPAD  2752      // 86*32; w2b zero-padded so h's pad cols contribute 0
#define NTOK  8192      // B*N = 4*2048
#define CAP   8192      // max tokens per expert
#define NSLOT 16384     // NTOK * TOP_K
#define MAXBLK 136      // sum_e ceil(M_e/128) <= 16384/128 + 8 = 136
#define NCH1  32        // gemm1 K chunks of 32 (K=1024)
#define NCH2  43        // gemm2 K chunks of 32 per split-K half (1376)

typedef __bf16 bf16x8 __attribute__((ext_vector_type(8)));
typedef float  floatx4 __attribute__((ext_vector_type(4)));

__device__ __forceinline__ unsigned short f2bf(float f) {
    union { float f; unsigned int u; } v; v.f = f;
    unsigned int u = v.u;
    unsigned int r = (u + 0x7fffu + ((u >> 16) & 1u)) >> 16;  // RNE
    return (unsigned short)r;
}

__device__ __forceinline__ float bf2f(unsigned short b) {
    union { unsigned int u; float f; } v; v.u = (unsigned int)b << 16;
    return v.f;
}

__device__ __forceinline__ void gl2lds16(const void* g, void* l) {
    __builtin_amdgcn_global_load_lds((const __attribute__((address_space(1))) void*)g,
                                     (__attribute__((address_space(3))) void*)l,
                                     16, 0, 0);
}

// ---------------- merged weight conversion (w1, w3, w2) + scalar init ----------------
__global__ void convert_w_kernel(const float* __restrict__ w1, const float* __restrict__ w3,
                                 const float* __restrict__ w2,
                                 unsigned short* __restrict__ w1b, unsigned short* __restrict__ w3b,
                                 unsigned short* __restrict__ w2b,
                                 int* __restrict__ counts, float* __restrict__ psum) {
    const int HALF = (NE * HID * DIM) / 4;   // 5,591,040 float4 chunks per w1/w3
    const int W13  = 2 * HALF;               // 11,182,080
    int gid = blockIdx.x * 256 + threadIdx.x;
    if (blockIdx.x == 0 && threadIdx.x < 64) {   // ordered before router (separate dispatch)
        counts[threadIdx.x & 15] = 0;
        psum[threadIdx.x & 15] = 0.f;
    }
    if (gid < W13) {
        const float* src; unsigned short* dst; int j;
        if (gid < HALF) { src = w1; dst = w1b; j = gid; }
        else            { src = w3; dst = w3b; j = gid - HALF; }
        float4 v = ((const float4*)src)[j];
        uint2 o;
        o.x = (unsigned)f2bf(v.x) | ((unsigned)f2bf(v.y) << 16);
        o.y = (unsigned)f2bf(v.z) | ((unsigned)f2bf(v.w) << 16);
        *(uint2*)(dst + (size_t)j * 4) = o;
    } else {
        int i = gid - W13;                   // 8192 rows * 688 chunks
        int r = i / 688;
        int c = (i - r * 688) * 4;
        const float* src = w2 + (size_t)r * HID;
        unsigned short q[4];
        if (c + 3 < HID) {                   // rows are 8B-aligned (2730*4 % 8 == 0)
            float2 v0 = *(const float2*)(src + c);
            float2 v1 = *(const float2*)(src + c + 2);
            q[0] = f2bf(v0.x); q[1] = f2bf(v0.y); q[2] = f2bf(v1.x); q[3] = f2bf(v1.y);
        } else {
#pragma unroll
            for (int j = 0; j < 4; ++j) {
                int col = c + j;
                q[j] = (col < HID) ? f2bf(src[col]) : (unsigned short)0;  // zero pad
            }
        }
        uint2 o;
        o.x = (unsigned)q[0] | ((unsigned)q[1] << 16);
        o.y = (unsigned)q[2] | ((unsigned)q[3] << 16);
        *(uint2*)(w2b + (size_t)r * HPAD + c) = o;
    }
}

// ---------------- router (also emits xb = bf16(x)) ----------------
__global__ void router_kernel(const float* __restrict__ x, const float* __restrict__ gw,
                              unsigned short* __restrict__ xb,
                              int* __restrict__ toks, int* __restrict__ meta,
                              float* __restrict__ tokw,
                              int* __restrict__ counts, float* __restrict__ psum) {
    __shared__ float gws[NE * DIM];        // 32 KB
    __shared__ float pblk[4][NE];
    int t = threadIdx.x;
    for (int i = t; i < NE * DIM; i += 256) gws[i] = gw[i];
    __syncthreads();

    int wv = t >> 6, lane = t & 63;
    int tok = blockIdx.x * 4 + wv;
    const float4* x4 = (const float4*)(x + (size_t)tok * DIM);
    uint2* xbrow = (uint2*)(xb + (size_t)tok * DIM);

    float p[NE];
#pragma unroll
    for (int e = 0; e < NE; ++e) p[e] = 0.f;
#pragma unroll
    for (int c = 0; c < 4; ++c) {
        float4 xv = x4[c * 64 + lane];
        uint2 o;
        o.x = (unsigned)f2bf(xv.x) | ((unsigned)f2bf(xv.y) << 16);
        o.y = (unsigned)f2bf(xv.z) | ((unsigned)f2bf(xv.w) << 16);
        xbrow[c * 64 + lane] = o;
#pragma unroll
        for (int e = 0; e < NE; ++e) {
            float4 gv = ((const float4*)(gws + e * DIM))[c * 64 + lane];
            p[e] += xv.x * gv.x + xv.y * gv.y + xv.z * gv.z + xv.w * gv.w;
        }
    }
#pragma unroll
    for (int e = 0; e < NE; ++e)
#pragma unroll
        for (int s = 32; s; s >>= 1) p[e] += __shfl_xor(p[e], s, 64);

    if (lane == 0) {
        float mx = p[0];
#pragma unroll
        for (int e = 1; e < NE; ++e) mx = fmaxf(mx, p[e]);
        float ex[NE], s = 0.f;
#pragma unroll
        for (int e = 0; e < NE; ++e) { ex[e] = __expf(p[e] - mx); s += ex[e]; }
        float inv = 1.f / s;
        int i1 = 0, i2 = 0; float v1 = -1.f, v2 = -1.f;
#pragma unroll
        for (int e = 0; e < NE; ++e) {
            float pe = ex[e] * inv;
            pblk[wv][e] = pe;
            if (pe > v1)      { v2 = v1; i2 = i1; v1 = pe; i1 = e; }
            else if (pe > v2) { v2 = pe; i2 = e; }
        }
        float wn = 1.f / (v1 + v2);
        int p1 = atomicAdd(&counts[i1], 1);
        toks[i1 * CAP + p1] = tok;
        meta[tok * 2]     = (i1 << 16) | p1;
        tokw[tok * 2]     = v1 * wn;
        int p2 = atomicAdd(&counts[i2], 1);
        toks[i2 * CAP + p2] = tok;
        meta[tok * 2 + 1] = (i2 << 16) | p2;
        tokw[tok * 2 + 1] = v2 * wn;
    }
    __syncthreads();
    if (t < NE) {
        float s = pblk[0][t] + pblk[1][t] + pblk[2][t] + pblk[3][t];
        atomicAdd(&psum[t], s);
    }
}

// finalize: prefix offsets, aux loss, and the live m-block table
__global__ void finalize_kernel(const int* __restrict__ counts, int* __restrict__ offs,
                                const float* __restrict__ psum, float* __restrict__ aux_out,
                                int* __restrict__ blk_e, int* __restrict__ blk_m0) {
    if (threadIdx.x == 0) {
        int off = 0, nb = 0;
        for (int e = 0; e < NE; ++e) {
            offs[e] = off;
            int M = counts[e];
            off += M;
            for (int m0 = 0; m0 < M; m0 += 128) { blk_e[nb] = e; blk_m0[nb] = m0; ++nb; }
        }
        for (; nb < MAXBLK; ++nb) { blk_e[nb] = 0; blk_m0[nb] = 0x7fffffff; }
        float s = 0.f;
        for (int e = 0; e < NE; ++e) {
            float d = psum[e] * (1.f / NTOK) - (1.f / NE);
            s += d * d;
        }
        aux_out[0] = 0.01f * s * (1.f / NE);
    }
}

// ---------------- stage-1: h = silu(x@w1^T) * (x@w3^T), gathered rows ----------------
// Proven 128x128-tile / 4-wave structure + minimum-2-phase pipeline (T3 recipe):
// BK=32 with a 2-slot LDS double buffer (48 KB total -> still 3 blocks/CU), next
// chunk's global_load_lds issued BEFORE computing the current chunk, counted
// s_waitcnt vmcnt(6) (never 0 mid-loop) + raw s_barrier (no implicit drain).
// LDS swizzle for 64B rows: phys16Bchunk = (lq + ((lr>>1)&3))&3; applied by
// pre-swizzling the per-lane GLOBAL source (gl2lds dest must be lane-linear).
// Per 16-lane group: 8 slots x 2 lanes = 2-way = free (m136).
// XCD swizzle: linear id (2992 = 8*22*17) -> q=id&7 (XCD class), all 22 n-blocks
// of one m-slot share the XCD -> A m-tile + weight-tile L2 reuse (baseline-proven).
__global__ __launch_bounds__(256, 2) void gemm1_kernel(
    const unsigned short* __restrict__ xb,
    const unsigned short* __restrict__ w1b,
    const unsigned short* __restrict__ w3b,
    unsigned short* __restrict__ h,
    const int* __restrict__ counts, const int* __restrict__ offs,
    const int* __restrict__ toks,
    const int* __restrict__ blk_e, const int* __restrict__ blk_m0) {
    const int id  = blockIdx.y * 22 + blockIdx.x;
    const int q   = id & 7;
    const int rest = id >> 3;               // < 374
    const int xp  = rest % 22;
    const int rr  = rest / 22;              // < 17
    const int slot = q * 17 + rr;           // m-slot, < 136
    const int e  = blk_e[slot];
    const int m0 = blk_m0[slot];
    const int M  = counts[e];
    if (m0 >= M) return;
    const int n0 = xp * 128;

    __shared__ unsigned short As[2][128 * 32];   // 16 KB
    __shared__ unsigned short B1s[2][128 * 32];  // 16 KB
    __shared__ unsigned short B3s[2][128 * 32];  // 16 KB

    const int t = threadIdx.x;
    const int wv = t >> 6, l = t & 63;
    // staging: issue i covers rows i*64 + wv*16 + (l>>2); lane writes phys chunk l&3
    const int r0 = wv * 16 + (l >> 2);
    const int r1 = r0 + 64;
    const int lc = ((l & 3) - ((l >> 3) & 3)) & 3;   // logical chunk staged at phys l&3
    const int st0 = (wv * 16) * 32 + l * 8;          // lane-linear LDS dest (ushorts)
    const int st1 = st0 + 64 * 32;
    const int* tl = toks + e * CAP;
    const unsigned short* a0p = xb + (size_t)tl[min(m0 + r0, M - 1)] * DIM + lc * 8;
    const unsigned short* a1p = xb + (size_t)tl[min(m0 + r1, M - 1)] * DIM + lc * 8;
    const unsigned short* w1e = w1b + (size_t)e * HID * DIM;
    const unsigned short* w3e = w3b + (size_t)e * HID * DIM;
    const unsigned short* b10p = w1e + (size_t)min(n0 + r0, HID - 1) * DIM + lc * 8;
    const unsigned short* b11p = w1e + (size_t)min(n0 + r1, HID - 1) * DIM + lc * 8;
    const unsigned short* b30p = w3e + (size_t)min(n0 + r0, HID - 1) * DIM + lc * 8;
    const unsigned short* b31p = w3e + (size_t)min(n0 + r1, HID - 1) * DIM + lc * 8;

    // MFMA fragment geometry (baseline): per-wave 64x64 dual
    const int lq = l >> 4, lr = l & 15;
    const int wm = (wv & 1) * 64, wn = (wv >> 1) * 64;
    const int phys = (lq + ((lr >> 1) & 3)) & 3;     // swizzled read chunk
    int aoff[4], boff[4];
#pragma unroll
    for (int mi = 0; mi < 4; ++mi) aoff[mi] = (wm + mi * 16 + lr) * 32 + phys * 8;
#pragma unroll
    for (int ni = 0; ni < 4; ++ni) boff[ni] = (wn + ni * 16 + lr) * 32 + phys * 8;

    floatx4 acc1[4][4], acc3[4][4];
#pragma unroll
    for (int a = 0; a < 4; ++a)
#pragma unroll
        for (int b = 0; b < 4; ++b) {
            acc1[a][b] = (floatx4){0.f, 0.f, 0.f, 0.f};
            acc3[a][b] = (floatx4){0.f, 0.f, 0.f, 0.f};
        }

    // prologue: stage chunk 0 into slot 0 (6 loads/thread)
    gl2lds16(a0p,  &As[0][st0]);  gl2lds16(a1p,  &As[0][st1]);
    gl2lds16(b10p, &B1s[0][st0]); gl2lds16(b11p, &B1s[0][st1]);
    gl2lds16(b30p, &B3s[0][st0]); gl2lds16(b31p, &B3s[0][st1]);

    for (int c = 0; c < NCH1; ++c) {
        const int buf = c & 1;
        if (c + 1 < NCH1) {
            const int ko = (c + 1) * 32;      // ushort k-offset of next chunk
            const int nb = buf ^ 1;
            gl2lds16(a0p + ko,  &As[nb][st0]);  gl2lds16(a1p + ko,  &As[nb][st1]);
            gl2lds16(b10p + ko, &B1s[nb][st0]); gl2lds16(b11p + ko, &B1s[nb][st1]);
            gl2lds16(b30p + ko, &B3s[nb][st0]); gl2lds16(b31p + ko, &B3s[nb][st1]);
            asm volatile("s_waitcnt vmcnt(6)" ::: "memory");   // chunk c landed; c+1 in flight
        } else {
            asm volatile("s_waitcnt vmcnt(0)" ::: "memory");
        }
        __builtin_amdgcn_sched_barrier(0);
        asm volatile("s_barrier" ::: "memory");
        const unsigned short* Az  = As[buf];
        const unsigned short* B1z = B1s[buf];
        const unsigned short* B3z = B3s[buf];
        bf16x8 af[4];
#pragma unroll
        for (int mi = 0; mi < 4; ++mi) af[mi] = *(const bf16x8*)(Az + aoff[mi]);
        __builtin_amdgcn_s_setprio(1);
#pragma unroll
        for (int ni = 0; ni < 4; ++ni) {
            bf16x8 b1 = *(const bf16x8*)(B1z + boff[ni]);
            bf16x8 b3 = *(const bf16x8*)(B3z + boff[ni]);
#pragma unroll
            for (int mi = 0; mi < 4; ++mi) {
                acc1[mi][ni] = __builtin_amdgcn_mfma_f32_16x16x32_bf16(af[mi], b1, acc1[mi][ni], 0, 0, 0);
                acc3[mi][ni] = __builtin_amdgcn_mfma_f32_16x16x32_bf16(af[mi], b3, acc3[mi][ni], 0, 0, 0);
            }
        }
        __builtin_amdgcn_s_setprio(0);
        __builtin_amdgcn_sched_barrier(0);
        asm volatile("s_barrier" ::: "memory");   // all reads of buf done before it's restaged
    }

    const int hb = offs[e];
#pragma unroll
    for (int mi = 0; mi < 4; ++mi) {
#pragma unroll
        for (int rg = 0; rg < 4; ++rg) {
            const int gm = m0 + wm + mi * 16 + lq * 4 + rg;
            if (gm >= M) continue;
            unsigned short* hrow = h + (size_t)(hb + gm) * HPAD;
#pragma unroll
            for (int ni = 0; ni < 4; ++ni) {
                const int col = n0 + wn + ni * 16 + lr;
                if (col >= HPAD) continue;
                float z1 = acc1[mi][ni][rg];
                float z3 = acc3[mi][ni][rg];
                float hv = z1 / (1.f + __expf(-z1)) * z3;   // silu(z1)*z3
                hrow[col] = f2bf(hv);
            }
        }
    }
}

// ---------------- stage-2: split-K=2, bf16 partials y[kh][slot] = h[slot,khalf] @ w2^T ----
// Same minimum-2-phase pipeline; 2 arrays -> 32 KB LDS -> 4 blocks/CU
// (__launch_bounds__(256,4)). vmcnt(4) counted wait.
// XCD swizzle: 2176 = 8*8*34 blocks. q=id&7, x'=(id>>3)&7, g=(id>>3)>>3 (<34);
// group G=q*34+g -> (slot = G%136, kh = G/136). Same-(slot,kh) n-blocks share XCD.
__global__ __launch_bounds__(256, 4) void gemm2_kernel(
    const unsigned short* __restrict__ h,
    const unsigned short* __restrict__ w2b,
    unsigned short* __restrict__ yh,            // [2][NSLOT][DIM] bf16 partials
    const int* __restrict__ counts, const int* __restrict__ offs,
    const int* __restrict__ blk_e, const int* __restrict__ blk_m0) {
    const int id = (blockIdx.z * MAXBLK + blockIdx.y) * 8 + blockIdx.x;
    const int q  = id & 7;
    const int rest = id >> 3;               // < 272
    const int xp = rest & 7;
    const int g  = rest >> 3;               // < 34
    const int G  = q * 34 + g;              // < 272
    const int slot = G % MAXBLK;
    const int kh   = G / MAXBLK;
    const int e  = blk_e[slot];
    const int m0 = blk_m0[slot];
    const int M  = counts[e];
    if (m0 >= M) return;
    const int n0 = xp * 128;
    const int hb = offs[e];

    __shared__ unsigned short As[2][128 * 32];   // 16 KB
    __shared__ unsigned short Bs[2][128 * 32];   // 16 KB

    const int t = threadIdx.x;
    const int wv = t >> 6, l = t & 63;
    const int r0 = wv * 16 + (l >> 2);
    const int r1 = r0 + 64;
    const int lc = ((l & 3) - ((l >> 3) & 3)) & 3;
    const int st0 = (wv * 16) * 32 + l * 8;
    const int st1 = st0 + 64 * 32;
    const int kb = kh * (NCH2 * 32);             // split-K element base
    const unsigned short* a0p = h + (size_t)(hb + min(m0 + r0, M - 1)) * HPAD + kb + lc * 8;
    const unsigned short* a1p = h + (size_t)(hb + min(m0 + r1, M - 1)) * HPAD + kb + lc * 8;
    const unsigned short* w2e = w2b + (size_t)e * DIM * HPAD;
    const unsigned short* b0p = w2e + (size_t)(n0 + r0) * HPAD + kb + lc * 8;
    const unsigned short* b1p = w2e + (size_t)(n0 + r1) * HPAD + kb + lc * 8;

    const int lq = l >> 4, lr = l & 15;
    const int wm = (wv & 1) * 64, wn = (wv >> 1) * 64;
    const int phys = (lq + ((lr >> 1) & 3)) & 3;
    int aoff[4], boff[4];
#pragma unroll
    for (int mi = 0; mi < 4; ++mi) aoff[mi] = (wm + mi * 16 + lr) * 32 + phys * 8;
#pragma unroll
    for (int ni = 0; ni < 4; ++ni) boff[ni] = (wn + ni * 16 + lr) * 32 + phys * 8;

    floatx4 acc[4][4];
#pragma unroll
    for (int a = 0; a < 4; ++a)
#pragma unroll
        for (int b = 0; b < 4; ++b) acc[a][b] = (floatx4){0.f, 0.f, 0.f, 0.f};

    gl2lds16(a0p, &As[0][st0]); gl2lds16(a1p, &As[0][st1]);
    gl2lds16(b0p, &Bs[0][st0]); gl2lds16(b1p, &Bs[0][st1]);

    for (int c = 0; c < NCH2; ++c) {
        const int buf = c & 1;
        if (c + 1 < NCH2) {
            const int ko = (c + 1) * 32;
            const int nb = buf ^ 1;
            gl2lds16(a0p + ko, &As[nb][st0]); gl2lds16(a1p + ko, &As[nb][st1]);
            gl2lds16(b0p + ko, &Bs[nb][st0]); gl2lds16(b1p + ko, &Bs[nb][st1]);
            asm volatile("s_waitcnt vmcnt(4)" ::: "memory");
        } else {
            asm volatile("s_waitcnt vmcnt(0)" ::: "memory");
        }
        __builtin_amdgcn_sched_barrier(0);
        asm volatile("s_barrier" ::: "memory");
        const unsigned short* Az = As[buf];
        const unsigned short* Bz = Bs[buf];
        bf16x8 af[4];
#pragma unroll
        for (int mi = 0; mi < 4; ++mi) af[mi] = *(const bf16x8*)(Az + aoff[mi]);
        __builtin_amdgcn_s_setprio(1);
#pragma unroll
        for (int ni = 0; ni < 4; ++ni) {
            bf16x8 bf = *(const bf16x8*)(Bz + boff[ni]);
#pragma unroll
            for (int mi = 0; mi < 4; ++mi)
                acc[mi][ni] = __builtin_amdgcn_mfma_f32_16x16x32_bf16(af[mi], bf, acc[mi][ni], 0, 0, 0);
        }
        __builtin_amdgcn_s_setprio(0);
        __builtin_amdgcn_sched_barrier(0);
        asm volatile("s_barrier" ::: "memory");
    }

    unsigned short* ybase = yh + (size_t)kh * NSLOT * DIM;
#pragma unroll
    for (int mi = 0; mi < 4; ++mi) {
#pragma unroll
        for (int rg = 0; rg < 4; ++rg) {
            const int gm = m0 + wm + mi * 16 + lq * 4 + rg;
            if (gm >= M) continue;
            unsigned short* yrow = ybase + (size_t)(hb + gm) * DIM;
#pragma unroll
            for (int ni = 0; ni < 4; ++ni)
                yrow[n0 + wn + ni * 16 + lr] = f2bf(acc[mi][ni][rg]);
        }
    }
}

// ---------------- combine: out[tok] = w0*(y0[s0]+y1[s0]) + w1*(y0[s1]+y1[s1]) ----------------
__global__ void combine_kernel(const unsigned short* __restrict__ yh,
                               const int* __restrict__ meta,
                               const float* __restrict__ tokw,
                               const int* __restrict__ offs,
                               float* __restrict__ out) {
    const int tok = blockIdx.x;
    const int t = threadIdx.x;                      // 256 threads x 4 floats = 1024
    const int m0 = meta[tok * 2], m1 = meta[tok * 2 + 1];
    const float w0 = tokw[tok * 2], w1 = tokw[tok * 2 + 1];
    const size_t r0 = (size_t)(offs[m0 >> 16] + (m0 & 0xffff)) * DIM;
    const size_t r1 = (size_t)(offs[m1 >> 16] + (m1 & 0xffff)) * DIM;
    const unsigned short* p0 = yh;
    const unsigned short* p1 = yh + (size_t)NSLOT * DIM;
    uint2 a0 = ((const uint2*)(p0 + r0))[t];
    uint2 a1 = ((const uint2*)(p1 + r0))[t];
    uint2 b0 = ((const uint2*)(p0 + r1))[t];
    uint2 b1 = ((const uint2*)(p1 + r1))[t];
    float4 o;
    o.x = w0 * (bf2f(a0.x & 0xffff) + bf2f(a1.x & 0xffff)) + w1 * (bf2f(b0.x & 0xffff) + bf2f(b1.x & 0xffff));
    o.y = w0 * (bf2f(a0.x >> 16)    + bf2f(a1.x >> 16))    + w1 * (bf2f(b0.x >> 16)    + bf2f(b1.x >> 16));
    o.z = w0 * (bf2f(a0.y & 0xffff) + bf2f(a1.y & 0xffff)) + w1 * (bf2f(b0.y & 0xffff) + bf2f(b1.y & 0xffff));
    o.w = w0 * (bf2f(a0.y >> 16)    + bf2f(a1.y >> 16))    + w1 * (bf2f(b0.y >> 16)    + bf2f(b1.y >> 16));
    ((float4*)(out + (size_t)tok * DIM))[t] = o;
}

extern "C" void kernel_launch(void* const* d_in, const int* in_sizes, int n_in,
                              void* d_out, int out_size, void* d_ws, size_t ws_size,
                              hipStream_t stream) {
    const float* x  = (const float*)d_in[0];
    const float* gw = (const float*)d_in[1];
    const float* w1 = (const float*)d_in[2];
    const float* w2 = (const float*)d_in[3];   // dict order: w1, w2, w3
    const float* w3 = (const float*)d_in[4];
    float* out = (float*)d_out;

    char* ws = (char*)d_ws;
    size_t o = 0;
    auto alloc = [&](size_t bytes) -> void* {
        void* p = ws + o;
        o += (bytes + 255) & ~(size_t)255;
        return p;
    };
    unsigned short* xb   = (unsigned short*)alloc((size_t)NTOK * DIM * 2);       // 16.8 MB
    unsigned short* w1b  = (unsigned short*)alloc((size_t)NE * HID * DIM * 2);   // 44.7 MB
    unsigned short* w3b  = (unsigned short*)alloc((size_t)NE * HID * DIM * 2);   // 44.7 MB
    unsigned short* w2b  = (unsigned short*)alloc((size_t)NE * DIM * HPAD * 2);  // 45.1 MB
    unsigned short* hbuf = (unsigned short*)alloc((size_t)NSLOT * HPAD * 2);     // 90.2 MB
    int*   toks   = (int*)alloc((size_t)NE * CAP * 4);
    int*   meta   = (int*)alloc((size_t)NTOK * 2 * 4);
    float* tokw   = (float*)alloc((size_t)NTOK * 2 * 4);
    int*   counts = (int*)alloc(256);
    float* psum   = (float*)alloc(256);
    int*   offs   = (int*)alloc(256);
    int*   blk_e  = (int*)alloc(MAXBLK * 4);
    int*   blk_m0 = (int*)alloc(MAXBLK * 4);
    if (o > ws_size) return;
    // bf16 split-K partials: 2 x 16384 x 1024 x 2 B = 67.1 MB, aliased over
    // xb+w1b+w3b (106.2 MB) -- all three are dead once gemm1 completes, and
    // gemm2 (which writes yh) is stream-ordered after gemm1.
    unsigned short* yh = (unsigned short*)xb;

    convert_w_kernel<<<65696, 256, 0, stream>>>(w1, w3, w2, w1b, w3b, w2b, counts, psum);
    router_kernel<<<2048, 256, 0, stream>>>(x, gw, xb, toks, meta, tokw, counts, psum);
    finalize_kernel<<<1, 64, 0, stream>>>(counts, offs, psum, out + (size_t)NTOK * DIM, blk_e, blk_m0);
    gemm1_kernel<<<dim3(22, MAXBLK, 1), 256, 0, stream>>>(xb, w1b, w3b, hbuf, counts, offs, toks, blk_e, blk_m0);
    gemm2_kernel<<<dim3(8, MAXBLK, 2), 256, 0, stream>>>(hbuf, w2b, yh, counts, offs, blk_e, blk_m0);
    combine_kernel<<<NTOK, 256, 0, stream>>>(yh, meta, tokw, offs, out);
}